// Round 4
// baseline (133.077 us; speedup 1.0000x reference)
//
#include <hip/hip_runtime.h>

// SparsePropMaxPool closed form (verified rounds 1-3, absmax=0):
//   ori_map_h[b,h,s,e] = max(x[b,h,s..e]) if (s, d=e-s) in SET else 0
//   SET: d in [0,15] any s | d odd in [17,31], s even | d%4==3 in [35,63], s%4==0
//   props_h[b,p,h] = max(x[b,h, s_p .. s_p+d_p])  (153 constant ranges, unions of
//     8-aligned width-8 windows -> T3[i]=max(x[i..i+7]) answers everything)
//   mask[b,0,s,e] = 1 at SET positions
// Out layout: props (64*153*512) | map (64*512*64*64) | mask (64*64*64)
//
// One kernel, uniform work per block (round-3 lesson: branch-local register
// spikes tax ALL blocks): block bid stages rows bh=bid*8..bid*8+7 (= props
// chunk h0=(bid&63)*8 of batch b=bid>>6) in LDS, builds T3 in LDS (flat
// registers), streams the 16KB map tile, then answers props queries from LDS.

#define B_ 64
#define H_ 512
#define N_ 64
#define NPROP 153
#define T3PITCH 65   // 65%32=1 -> hoff-stride-65 reads conflict-free

__device__ __forceinline__ bool in_set(int s, int d) {
    if (d < 0) return false;
    if (d <= 15) return true;
    if (d <= 31) return (d & 1) && ((s & 1) == 0);        // d=17,19..31 odd, s even
    return (d >= 35) && ((d & 3) == 3) && ((s & 3) == 0); // d=35,39..63, s%4==0
}

__device__ __forceinline__ void decode_prop(int p, int& s, int& nw) {
    // nw = number of width-8 windows = (d+1)/8
    if (p < 57)       { s = p;           nw = 1; }
    else if (p < 106) { s = p - 57;      nw = 2; }
    else if (p < 127) { s = 2*(p - 106); nw = 3; }
    else if (p < 144) { s = 2*(p - 127); nw = 4; }
    else if (p < 149) { s = 4*(p - 144); nw = 6; }
    else if (p < 152) { s = 4*(p - 149); nw = 7; }
    else              { s = 0;           nw = 8; }
}

__global__ __launch_bounds__(128) void fused_kernel(const float* __restrict__ x,
                                                    float* __restrict__ out_props,
                                                    float* __restrict__ out_map,
                                                    float* __restrict__ out_mask) {
    const int tid = threadIdx.x;    // 0..127
    const int bid = blockIdx.x;     // 0..4095
    const int g   = tid >> 4;       // map row within block 0..7
    const int t   = tid & 15;       // float4 column 0..15

    __shared__ __align__(16) float xs[8][72];       // 288B pitch: conflict-free
    __shared__ float T3s[8][T3PITCH];               // T3s[row][i]=max(xs[row][i..i+7])

    float4 xv = reinterpret_cast<const float4*>(x)[bid * 128 + tid];
    *reinterpret_cast<float4*>(&xs[g][4 * t]) = xv;
    __syncthreads();

    // ---- build T3 (8 rows x 57): wave-row mapping, stride-1 lanes ----
    {
        const int i  = tid & 63;
        const int g2 = tid >> 6;    // wave id
        if (i < 57) {
            #pragma unroll
            for (int it = 0; it < 4; ++it) {
                const int row = it * 2 + g2;
                float m = xs[row][i];
                #pragma unroll
                for (int j = 1; j < 8; ++j) m = fmaxf(m, xs[row][i + j]);
                T3s[row][i] = m;
            }
        }
    }
    // (consumed after the map loop's __syncthreads)

    // ---- map: 8 rows, float4 stores — the BW backbone ----
    {
        const size_t bh = (size_t)bid * 8 + g;
        float4* mrow = reinterpret_cast<float4*>(out_map + bh * (size_t)(N_ * N_));
        const int e0 = 4 * t;
        float vx = 0.f, vy = 0.f, vz = 0.f, vw = 0.f;
        #pragma unroll
        for (int s = N_ - 1; s >= 0; --s) {   // v_j = max(x[s..e_j]), reset at s==e_j
            const float mv = xs[g][s];
            vx = (s == e0 + 0) ? mv : fmaxf(vx, mv);
            vy = (s == e0 + 1) ? mv : fmaxf(vy, mv);
            vz = (s == e0 + 2) ? mv : fmaxf(vz, mv);
            vw = (s == e0 + 3) ? mv : fmaxf(vw, mv);
            float4 w;
            w.x = in_set(s, e0 + 0 - s) ? vx : 0.f;
            w.y = in_set(s, e0 + 1 - s) ? vy : 0.f;
            w.z = in_set(s, e0 + 2 - s) ? vz : 0.f;
            w.w = in_set(s, e0 + 3 - s) ? vw : 0.f;
            mrow[s * 16 + t] = w;              // 4 rows x 256B per wave-instruction
        }
    }

    __syncthreads();   // T3s ready

    // ---- props: 153 p x 8 h per block, answered from T3s ----
    {
        const int b  = bid >> 6;
        const int h0 = (bid & 63) * 8;
        float* po = out_props + (size_t)b * NPROP * H_ + h0;
        #pragma unroll
        for (int k = tid; k < NPROP * 8; k += 128) {
            const int p = k >> 3, hoff = k & 7;
            int s, nw; decode_prop(p, s, nw);
            float m = T3s[hoff][s];
            for (int j = 1; j < nw; ++j) m = fmaxf(m, T3s[hoff][s + 8 * j]);
            po[(size_t)p * H_ + hoff] = m;     // 8x 32B chunks per wave
        }
    }

    // ---- mask: one block per b ----
    if ((bid & 63) == 0) {
        float* mk = out_mask + (size_t)(bid >> 6) * (N_ * N_);
        #pragma unroll
        for (int i = 0; i < 32; ++i) {
            const int idx = tid + i * 128;     // idx = s*64 + e
            const int s = idx >> 6, e = idx & 63;
            mk[idx] = in_set(s, e - s) ? 1.0f : 0.0f;
        }
    }
}

extern "C" void kernel_launch(void* const* d_in, const int* in_sizes, int n_in,
                              void* d_out, int out_size, void* d_ws, size_t ws_size,
                              hipStream_t stream) {
    const float* x = (const float*)d_in[0];   // (64, 512, 64) f32
    float* out       = (float*)d_out;
    float* out_props = out;                                   // 5,013,504
    float* out_map   = out + (size_t)B_ * NPROP * H_;         // 134,217,728
    float* out_mask  = out_map + (size_t)B_ * H_ * N_ * N_;   // 262,144

    fused_kernel<<<dim3(B_ * H_ / 8), dim3(128), 0, stream>>>(x, out_props, out_map, out_mask);
}

// Round 5
// 106.276 us; speedup vs baseline: 1.2522x; 1.2522x over previous
//
#include <hip/hip_runtime.h>

// SparsePropMaxPool closed form (verified rounds 1-4, absmax=0):
//   ori_map_h[b,h,s,e] = max(x[b,h,s..e]) if (s, d=e-s) in SET else 0
//   SET: d in [0,15] any s | d odd in [17,31], s even | d%4==3 in [35,63], s%4==0
//   props_h[b,p,h] = max(x[b,h, s_p .. s_p+d_p])  (153 constant ranges)
//   mask[b,0,s,e] = 1 at SET positions
// Out layout: props (64*153*512) | map (64*512*64*64) | mask (64*64*64)
//
// Round-3/4 lesson: do NOT fuse props into the map kernel (register spike or
// post-store barrier both tax the BW backbone). Two kernels, round-2 skeleton:
//   1) props kernel (512 blocks, heavy VGPR but isolated, ~5us)
//   2) map kernel: 256-thr blocks, nontemporal float4 stores (streaming 537MB)

#define B_ 64
#define H_ 512
#define N_ 64
#define NPROP 153

typedef float f4 __attribute__((ext_vector_type(4)));

__device__ __forceinline__ bool in_set(int s, int d) {
    if (d < 0) return false;
    if (d <= 15) return true;
    if (d <= 31) return (d & 1) && ((s & 1) == 0);        // d=17,19..31 odd, s even
    return (d >= 35) && ((d & 3) == 3) && ((s & 3) == 0); // d=35,39..63, s%4==0
}

// ---------------- map kernel: 16 bh-rows per 256-thread block, nt float4 stores
__global__ __launch_bounds__(256) void map_kernel(const float* __restrict__ x,
                                                  float* __restrict__ out_map) {
    const int tid = threadIdx.x;        // 0..255
    const int g   = tid >> 4;           // row within block 0..15
    const int t   = tid & 15;           // float4 column 0..15
    const size_t bh = (size_t)blockIdx.x * 16 + g;

    // [16][72]: row pitch 288B; wave reads xs[g][s] at 4 distinct banks -> free
    __shared__ __align__(16) float xs[16][72];
    f4 xv = reinterpret_cast<const f4*>(x)[blockIdx.x * 256 + tid];
    *reinterpret_cast<f4*>(&xs[g][4 * t]) = xv;
    __syncthreads();

    f4* mrow = reinterpret_cast<f4*>(out_map + bh * (size_t)(N_ * N_));
    const int e0 = 4 * t;
    float vx = 0.f, vy = 0.f, vz = 0.f, vw = 0.f;
    #pragma unroll
    for (int s = N_ - 1; s >= 0; --s) {   // v_j = max(x[s..e_j]), reset at s==e_j
        const float mv = xs[g][s];
        vx = (s == e0 + 0) ? mv : fmaxf(vx, mv);
        vy = (s == e0 + 1) ? mv : fmaxf(vy, mv);
        vz = (s == e0 + 2) ? mv : fmaxf(vz, mv);
        vw = (s == e0 + 3) ? mv : fmaxf(vw, mv);
        f4 w;
        w.x = in_set(s, e0 + 0 - s) ? vx : 0.f;   // s,j compile-time -> t-compares
        w.y = in_set(s, e0 + 1 - s) ? vy : 0.f;
        w.z = in_set(s, e0 + 2 - s) ? vz : 0.f;
        w.w = in_set(s, e0 + 3 - s) ? vw : 0.f;
        __builtin_nontemporal_store(w, &mrow[s * 16 + t]);  // bypass L2 allocate
    }
}

// ---------------- props+mask kernel: lane = h, contiguous 256B stores ----------
// All 153 ranges are unions of 8-aligned length-8 windows -> T3[i]=max(x[i..i+7])
// answers everything. Fully unrolled, static indices only (registers).
__global__ __launch_bounds__(64) void props_kernel(const float* __restrict__ x,
                                                   float* __restrict__ out_props,
                                                   float* __restrict__ out_mask) {
    const int lane = threadIdx.x;            // h within 64-chunk
    const int b = blockIdx.x >> 3;
    const int c = blockIdx.x & 7;
    const int h = c * 64 + lane;

    const f4* xr = reinterpret_cast<const f4*>(x + ((size_t)b * H_ + h) * N_);
    float r[64];
    #pragma unroll
    for (int k = 0; k < 16; ++k) {
        f4 v = xr[k];
        r[4*k+0] = v.x; r[4*k+1] = v.y; r[4*k+2] = v.z; r[4*k+3] = v.w;
    }
    float a[63];
    #pragma unroll
    for (int i = 0; i < 63; ++i) a[i] = fmaxf(r[i], r[i+1]);
    float bb[61];
    #pragma unroll
    for (int i = 0; i < 61; ++i) bb[i] = fmaxf(a[i], a[i+2]);
    float T3[57];                            // T3[i] = max(x[i..i+7])
    #pragma unroll
    for (int i = 0; i < 57; ++i) T3[i] = fmaxf(bb[i], bb[i+4]);

    float* po = out_props + (size_t)b * NPROP * H_ + h;
    int p = 0;
    #pragma unroll
    for (int s = 0; s < 57; ++s)              // d=7
        __builtin_nontemporal_store(T3[s], &po[(size_t)(p++) * H_]);
    #pragma unroll
    for (int s = 0; s < 49; ++s)              // d=15
        __builtin_nontemporal_store(fmaxf(T3[s], T3[s + 8]), &po[(size_t)(p++) * H_]);
    #pragma unroll
    for (int s = 0; s <= 40; s += 2)          // d=23
        __builtin_nontemporal_store(fmaxf(fmaxf(T3[s], T3[s + 8]), T3[s + 16]),
                                    &po[(size_t)(p++) * H_]);
    #pragma unroll
    for (int s = 0; s <= 32; s += 2)          // d=31
        __builtin_nontemporal_store(
            fmaxf(fmaxf(T3[s], T3[s + 8]), fmaxf(T3[s + 16], T3[s + 24])),
            &po[(size_t)(p++) * H_]);
    #pragma unroll
    for (int s = 0; s <= 16; s += 4) {        // d=47
        float m = T3[s];
        #pragma unroll
        for (int j = 8; j <= 40; j += 8) m = fmaxf(m, T3[s + j]);
        __builtin_nontemporal_store(m, &po[(size_t)(p++) * H_]);
    }
    #pragma unroll
    for (int s = 0; s <= 8; s += 4) {         // d=55
        float m = T3[s];
        #pragma unroll
        for (int j = 8; j <= 48; j += 8) m = fmaxf(m, T3[s + j]);
        __builtin_nontemporal_store(m, &po[(size_t)(p++) * H_]);
    }
    {                                         // d=63
        float m = T3[0];
        #pragma unroll
        for (int j = 8; j <= 56; j += 8) m = fmaxf(m, T3[j]);
        __builtin_nontemporal_store(m, &po[(size_t)p * H_]);
    }

    if (c == 0) {                             // mask: per-b content
        float* mk = out_mask + (size_t)b * (N_ * N_);
        #pragma unroll
        for (int s = 0; s < N_; ++s)
            mk[s * N_ + lane] = in_set(s, lane - s) ? 1.0f : 0.0f;
    }
}

extern "C" void kernel_launch(void* const* d_in, const int* in_sizes, int n_in,
                              void* d_out, int out_size, void* d_ws, size_t ws_size,
                              hipStream_t stream) {
    const float* x = (const float*)d_in[0];   // (64, 512, 64) f32
    float* out       = (float*)d_out;
    float* out_props = out;                                   // 5,013,504
    float* out_map   = out + (size_t)B_ * NPROP * H_;         // 134,217,728
    float* out_mask  = out_map + (size_t)B_ * H_ * N_ * N_;   // 262,144

    props_kernel<<<dim3(B_ * (H_ / 64)), dim3(64), 0, stream>>>(x, out_props, out_mask);
    map_kernel<<<dim3(B_ * H_ / 16), dim3(256), 0, stream>>>(x, out_map);
}

// Round 6
// 101.485 us; speedup vs baseline: 1.3113x; 1.0472x over previous
//
#include <hip/hip_runtime.h>

// SparsePropMaxPool closed form (verified rounds 1-5, absmax=0):
//   ori_map_h[b,h,s,e] = max(x[b,h,s..e]) if (s, d=e-s) in SET else 0
//   SET: d in [0,15] any s | d odd in [17,31], s even | d%4==3 in [35,63], s%4==0
//   props_h[b,p,h] = max(x[b,h, s_p .. s_p+d_p])  (153 constant ranges)
//   mask[b,0,s,e] = 1 at SET positions
// Out layout: props (64*153*512) | map (64*512*64*64) | mask (64*64*64)
//
// Lessons: R3 (props prologue + map in same blocks) and R4 (post-store barrier)
// both regressed; R5 two-kernel = 106us but serializes ~5-10us of props.
// Fill kernel sustains 6.7TB/s at 3.4 waves/CU -> store BW needs few waves, so
// fuse via HETEROGENEOUS grid: blocks 0..63 do ONLY props+mask for one b each
// (hidden under map BW), blocks 64..2111 do ONLY the 16-row map tile (no
// barrier after stores, no extra work). One dispatch, no serial phase.

#define B_ 64
#define H_ 512
#define N_ 64
#define NPROP 153

typedef float f4 __attribute__((ext_vector_type(4)));

__device__ __forceinline__ bool in_set(int s, int d) {
    if (d < 0) return false;
    if (d <= 15) return true;
    if (d <= 31) return (d & 1) && ((s & 1) == 0);        // d=17,19..31 odd, s even
    return (d >= 35) && ((d & 3) == 3) && ((s & 3) == 0); // d=35,39..63, s%4==0
}

__global__ __launch_bounds__(256) void fused_kernel(const float* __restrict__ x,
                                                    float* __restrict__ out_props,
                                                    float* __restrict__ out_map,
                                                    float* __restrict__ out_mask) {
    const int tid = threadIdx.x;    // 0..255
    const int bid = blockIdx.x;     // 0..2111

    __shared__ __align__(16) float xs[16][72];   // map path only (4.6KB)

    if (bid < B_) {
        // ---------------- props + mask block: one batch b ----------------
        const int b = bid;

        // mask: 64x64 = 1024 f4, 4 per thread
        f4* mk = reinterpret_cast<f4*>(out_mask + (size_t)b * (N_ * N_));
        #pragma unroll
        for (int i = 0; i < 4; ++i) {
            const int idx = tid + 256 * i;   // f4 index; s = idx>>4, c = idx&15
            const int s = idx >> 4, c = idx & 15;
            f4 w;
            w.x = in_set(s, 4 * c + 0 - s) ? 1.f : 0.f;
            w.y = in_set(s, 4 * c + 1 - s) ? 1.f : 0.f;
            w.z = in_set(s, 4 * c + 2 - s) ? 1.f : 0.f;
            w.w = in_set(s, 4 * c + 3 - s) ? 1.f : 0.f;
            __builtin_nontemporal_store(w, &mk[idx]);
        }

        // props: 512 h rows, 2 per thread, sequential (keep VGPR low)
        #pragma unroll 1
        for (int half = 0; half < 2; ++half) {
            const int h = tid + 256 * half;
            const f4* xr = reinterpret_cast<const f4*>(x + ((size_t)b * H_ + h) * N_);
            float r[64];
            #pragma unroll
            for (int k = 0; k < 16; ++k) {
                f4 v = xr[k];
                r[4*k+0] = v.x; r[4*k+1] = v.y; r[4*k+2] = v.z; r[4*k+3] = v.w;
            }
            float a[63];
            #pragma unroll
            for (int i = 0; i < 63; ++i) a[i] = fmaxf(r[i], r[i+1]);
            float m4[61];
            #pragma unroll
            for (int i = 0; i < 61; ++i) m4[i] = fmaxf(a[i], a[i+2]);
            float T3[57];                    // T3[i] = max(x[i..i+7])
            #pragma unroll
            for (int i = 0; i < 57; ++i) T3[i] = fmaxf(m4[i], m4[i+4]);

            float* po = out_props + (size_t)b * NPROP * H_ + h;
            int p = 0;
            #pragma unroll
            for (int s = 0; s < 57; ++s)              // d=7
                __builtin_nontemporal_store(T3[s], &po[(size_t)(p++) * H_]);
            #pragma unroll
            for (int s = 0; s < 49; ++s)              // d=15
                __builtin_nontemporal_store(fmaxf(T3[s], T3[s + 8]),
                                            &po[(size_t)(p++) * H_]);
            #pragma unroll
            for (int s = 0; s <= 40; s += 2)          // d=23
                __builtin_nontemporal_store(fmaxf(fmaxf(T3[s], T3[s + 8]), T3[s + 16]),
                                            &po[(size_t)(p++) * H_]);
            #pragma unroll
            for (int s = 0; s <= 32; s += 2)          // d=31
                __builtin_nontemporal_store(
                    fmaxf(fmaxf(T3[s], T3[s + 8]), fmaxf(T3[s + 16], T3[s + 24])),
                    &po[(size_t)(p++) * H_]);
            #pragma unroll
            for (int s = 0; s <= 16; s += 4) {        // d=47
                float m = T3[s];
                #pragma unroll
                for (int j = 8; j <= 40; j += 8) m = fmaxf(m, T3[s + j]);
                __builtin_nontemporal_store(m, &po[(size_t)(p++) * H_]);
            }
            #pragma unroll
            for (int s = 0; s <= 8; s += 4) {         // d=55
                float m = T3[s];
                #pragma unroll
                for (int j = 8; j <= 48; j += 8) m = fmaxf(m, T3[s + j]);
                __builtin_nontemporal_store(m, &po[(size_t)(p++) * H_]);
            }
            {                                         // d=63
                float m = T3[0];
                #pragma unroll
                for (int j = 8; j <= 56; j += 8) m = fmaxf(m, T3[j]);
                __builtin_nontemporal_store(m, &po[(size_t)p * H_]);
            }
        }
        return;
    }

    // ---------------- map block: 16 bh-rows, nt float4 stores ----------------
    const int mb = bid - B_;            // 0..2047
    const int g  = tid >> 4;            // row within block 0..15
    const int t  = tid & 15;            // float4 column 0..15
    const size_t bh = (size_t)mb * 16 + g;

    f4 xv = reinterpret_cast<const f4*>(x)[mb * 256 + tid];
    *reinterpret_cast<f4*>(&xs[g][4 * t]) = xv;
    __syncthreads();

    f4* mrow = reinterpret_cast<f4*>(out_map + bh * (size_t)(N_ * N_));
    const int e0 = 4 * t;
    float vx = 0.f, vy = 0.f, vz = 0.f, vw = 0.f;
    #pragma unroll
    for (int s = N_ - 1; s >= 0; --s) {   // v_j = max(x[s..e_j]), reset at s==e_j
        const float mv = xs[g][s];
        vx = (s == e0 + 0) ? mv : fmaxf(vx, mv);
        vy = (s == e0 + 1) ? mv : fmaxf(vy, mv);
        vz = (s == e0 + 2) ? mv : fmaxf(vz, mv);
        vw = (s == e0 + 3) ? mv : fmaxf(vw, mv);
        f4 w;
        w.x = in_set(s, e0 + 0 - s) ? vx : 0.f;   // s compile-time -> t-compares
        w.y = in_set(s, e0 + 1 - s) ? vy : 0.f;
        w.z = in_set(s, e0 + 2 - s) ? vz : 0.f;
        w.w = in_set(s, e0 + 3 - s) ? vw : 0.f;
        __builtin_nontemporal_store(w, &mrow[s * 16 + t]);
    }
}

extern "C" void kernel_launch(void* const* d_in, const int* in_sizes, int n_in,
                              void* d_out, int out_size, void* d_ws, size_t ws_size,
                              hipStream_t stream) {
    const float* x = (const float*)d_in[0];   // (64, 512, 64) f32
    float* out       = (float*)d_out;
    float* out_props = out;                                   // 5,013,504
    float* out_map   = out + (size_t)B_ * NPROP * H_;         // 134,217,728
    float* out_mask  = out_map + (size_t)B_ * H_ * N_ * N_;   // 262,144

    fused_kernel<<<dim3(B_ + B_ * H_ / 16), dim3(256), 0, stream>>>(
        x, out_props, out_map, out_mask);
}